// Round 1
// baseline (3561.213 us; speedup 1.0000x reference)
//
#include <hip/hip_runtime.h>

// GraphConv x5 on MI355X.
// Structure: build CSR (dst-sorted edges) once per call (hist+scan+scatter),
// then 4 atomic-free aggregation passes. Middle layers fuse gather + dense
// transform (+bias+relu) in one kernel with weights in padded LDS.

#define NN 100000
#define NE 1600000
#define HID 64
#define SCAN_B 512

__global__ void k_hist(const int* __restrict__ dst, int* __restrict__ counts) {
    int e = blockIdx.x * blockDim.x + threadIdx.x;
    if (e < NE) atomicAdd(&counts[dst[e]], 1);
}

__global__ void k_scan1(const int* __restrict__ counts, int* __restrict__ offs,
                        int* __restrict__ bsums) {
    __shared__ int tmp[SCAN_B];
    int tid = threadIdx.x;
    int i = blockIdx.x * SCAN_B + tid;
    int v = (i < NN) ? counts[i] : 0;
    int acc = v;
    tmp[tid] = v;
    __syncthreads();
    for (int off = 1; off < SCAN_B; off <<= 1) {
        int t = (tid >= off) ? tmp[tid - off] : 0;
        __syncthreads();
        acc += t;
        tmp[tid] = acc;
        __syncthreads();
    }
    if (i < NN) offs[i] = acc - v;                 // local exclusive
    if (tid == SCAN_B - 1) bsums[blockIdx.x] = acc; // block total
}

__global__ void k_scan2(int* __restrict__ bsums, int nb) {
    __shared__ int tmp[256];
    int tid = threadIdx.x;
    int v = (tid < nb) ? bsums[tid] : 0;
    int acc = v;
    tmp[tid] = v;
    __syncthreads();
    for (int off = 1; off < 256; off <<= 1) {
        int t = (tid >= off) ? tmp[tid - off] : 0;
        __syncthreads();
        acc += t;
        tmp[tid] = acc;
        __syncthreads();
    }
    if (tid < nb) bsums[tid] = acc - v;            // exclusive block prefix
}

__global__ void k_scan3(int* __restrict__ offs, const int* __restrict__ bsums,
                        int* __restrict__ cursor) {
    int i = blockIdx.x * blockDim.x + threadIdx.x;
    if (i < NN) {
        int v = offs[i] + bsums[i / SCAN_B];
        offs[i] = v;
        cursor[i] = v;
    }
    if (i == 0) offs[NN] = NE;
}

__global__ void k_scatter(const int* __restrict__ src, const int* __restrict__ dst,
                          const float* __restrict__ w, int* __restrict__ cursor,
                          int* __restrict__ ssrc, float* __restrict__ ssw) {
    int e = blockIdx.x * blockDim.x + threadIdx.x;
    if (e < NE) {
        int d = dst[e];
        int pos = atomicAdd(&cursor[d], 1);
        ssrc[pos] = src[e];
        ssw[pos]  = w[e];
    }
}

// scalar segment-sum: out[i] = sum_{e into i} w_e * val[src_e]
__global__ void k_agg_scalar(const int* __restrict__ offs, const int* __restrict__ ssrc,
                             const float* __restrict__ ssw, const float* __restrict__ val,
                             float* __restrict__ out) {
    int i = blockIdx.x * blockDim.x + threadIdx.x;
    if (i >= NN) return;
    float acc = 0.f;
    int b = offs[i], e = offs[i + 1];
    for (int j = b; j < e; j++) acc += ssw[j] * val[ssrc[j]];
    out[i] = acc;
}

// h0[i][c] = relu(agg0[i]*Wrel0[c] + brel0[c] + x[i]*Wroot0[c])
__global__ void k_layer0(const float* __restrict__ agg0, const float* __restrict__ x,
                         const float* __restrict__ Wrel0, const float* __restrict__ brel0,
                         const float* __restrict__ Wroot0, float* __restrict__ h) {
    int idx = blockIdx.x * blockDim.x + threadIdx.x;  // NN*64 exact
    int i = idx >> 6, c = idx & 63;
    float v = agg0[i] * Wrel0[c] + brel0[c] + x[i] * Wroot0[c];
    h[idx] = v > 0.f ? v : 0.f;
}

// Fused middle layer: per-node gather (wave per node, lane = channel) +
// dense 64x64 transform from LDS weights + bias + relu.
#define NODES_PER_BLOCK 64
__global__ __launch_bounds__(256) void k_mid(
        const int* __restrict__ offs, const int* __restrict__ ssrc,
        const float* __restrict__ ssw, const float* __restrict__ hin,
        const float* __restrict__ Wrel, const float* __restrict__ brel,
        const float* __restrict__ Wroot, float* __restrict__ hout) {
    __shared__ float sWrel[64 * 65];   // +1 pad: bank = (lane+k)%32 -> 2-way (free)
    __shared__ float sWroot[64 * 65];
    __shared__ float sAgg[4][64];
    __shared__ float sRoot[4][64];

    int tid = threadIdx.x;
    int wv = tid >> 6, lane = tid & 63;

    for (int t = tid; t < 4096; t += 256) {
        int r = t >> 6, c = t & 63;
        sWrel[r * 65 + c]  = Wrel[t];
        sWroot[r * 65 + c] = Wroot[t];
    }
    float bias = brel[lane];
    __syncthreads();

    int base = blockIdx.x * NODES_PER_BLOCK;
    for (int t = 0; t < NODES_PER_BLOCK / 4; t++) {
        int node = base + t * 4 + wv;
        float agg = 0.f, root = 0.f;
        if (node < NN) {
            int s0 = offs[node], s1 = offs[node + 1];
            for (int j = s0; j < s1; j++) {
                agg += ssw[j] * hin[ssrc[j] * 64 + lane];  // 256B coalesced row
            }
            root = hin[node * 64 + lane];
        }
        sAgg[wv][lane] = agg;
        sRoot[wv][lane] = root;
        __syncthreads();
        float acc = bias;   // lane = output channel
        #pragma unroll
        for (int k = 0; k < 64; k++) {
            acc += sWrel[lane * 65 + k] * sAgg[wv][k]
                 + sWroot[lane * 65 + k] * sRoot[wv][k];
        }
        __syncthreads();
        if (node < NN) hout[node * 64 + lane] = acc > 0.f ? acc : 0.f;
    }
}

// last layer scalars: s[i]=dot(h[i],WrelL), r[i]=dot(h[i],WrootL); wave per node
__global__ void k_lastdot(const float* __restrict__ h, const float* __restrict__ WrelL,
                          const float* __restrict__ WrootL, float* __restrict__ sarr,
                          float* __restrict__ rarr) {
    int g = blockIdx.x * blockDim.x + threadIdx.x;
    int node = g >> 6, lane = g & 63;
    if (node >= NN) return;
    float v = h[node * 64 + lane];
    float a = v * WrelL[lane];
    float c = v * WrootL[lane];
    for (int o = 32; o > 0; o >>= 1) {
        a += __shfl_down(a, o, 64);
        c += __shfl_down(c, o, 64);
    }
    if (lane == 0) { sarr[node] = a; rarr[node] = c; }
}

__global__ void k_last(const int* __restrict__ offs, const int* __restrict__ ssrc,
                       const float* __restrict__ ssw, const float* __restrict__ sarr,
                       const float* __restrict__ rarr, const float* __restrict__ brelL,
                       float* __restrict__ out) {
    int i = blockIdx.x * blockDim.x + threadIdx.x;
    if (i >= NN) return;
    float acc = rarr[i] + brelL[0];
    int b = offs[i], e = offs[i + 1];
    for (int j = b; j < e; j++) acc += ssw[j] * sarr[ssrc[j]];
    out[i] = acc;
}

extern "C" void kernel_launch(void* const* d_in, const int* in_sizes, int n_in,
                              void* d_out, int out_size, void* d_ws, size_t ws_size,
                              hipStream_t stream) {
    const float* x        = (const float*)d_in[0];
    const int*   ei       = (const int*)d_in[1];
    const float* ew       = (const float*)d_in[2];
    const float* Wrel0    = (const float*)d_in[3];
    const float* brel0    = (const float*)d_in[4];
    const float* Wroot0   = (const float*)d_in[5];
    const float* Wrel_mid = (const float*)d_in[6];
    const float* brel_mid = (const float*)d_in[7];
    const float* Wroot_mid= (const float*)d_in[8];
    const float* WrelL    = (const float*)d_in[9];
    const float* brelL    = (const float*)d_in[10];
    const float* WrootL   = (const float*)d_in[11];
    float* out = (float*)d_out;

    const int* src  = ei;          // edge_index[0]
    const int* dstp = ei + NE;     // edge_index[1]

    char* w = (char*)d_ws;
    size_t o = 0;
    auto alloc = [&](size_t b) -> void* {
        void* r = (void*)(w + o);
        o += (b + 255) & ~(size_t)255;
        return r;
    };
    int*   counts = (int*)alloc((size_t)NN * 4);        // reused as cursor
    int*   offs   = (int*)alloc((size_t)(NN + 1) * 4);
    int*   bsums  = (int*)alloc(256 * 4);
    int*   ssrc   = (int*)alloc((size_t)NE * 4);
    float* ssw    = (float*)alloc((size_t)NE * 4);
    float* agg0   = (float*)alloc((size_t)NN * 4);
    float* sarr   = (float*)alloc((size_t)NN * 4);
    float* rarr   = (float*)alloc((size_t)NN * 4);
    float* bufA   = (float*)alloc((size_t)NN * HID * 4);
    float* bufB   = (float*)alloc((size_t)NN * HID * 4);

    hipMemsetAsync(counts, 0, (size_t)NN * 4, stream);
    int nb1 = (NN + SCAN_B - 1) / SCAN_B;   // 196

    k_hist<<<(NE + 255) / 256, 256, 0, stream>>>(dstp, counts);
    k_scan1<<<nb1, SCAN_B, 0, stream>>>(counts, offs, bsums);
    k_scan2<<<1, 256, 0, stream>>>(bsums, nb1);
    k_scan3<<<(NN + 255) / 256, 256, 0, stream>>>(offs, bsums, counts);
    k_scatter<<<(NE + 255) / 256, 256, 0, stream>>>(src, dstp, ew, counts, ssrc, ssw);

    // layer 0 (1-channel input)
    k_agg_scalar<<<(NN + 255) / 256, 256, 0, stream>>>(offs, ssrc, ssw, x, agg0);
    k_layer0<<<(NN * HID) / 256, 256, 0, stream>>>(agg0, x, Wrel0, brel0, Wroot0, bufA);

    // 3 fused middle layers, ping-pong bufA/bufB
    const float* hin = bufA;
    float* hout = bufB;
    for (int l = 0; l < 3; l++) {
        k_mid<<<(NN + NODES_PER_BLOCK - 1) / NODES_PER_BLOCK, 256, 0, stream>>>(
            offs, ssrc, ssw, hin,
            Wrel_mid + (size_t)l * HID * HID, brel_mid + (size_t)l * HID,
            Wroot_mid + (size_t)l * HID * HID, hout);
        const float* t = hout; hout = (float*)hin; hin = t;
    }

    // last layer: push WrelL through segment_sum (linearity) -> scalar aggregation
    k_lastdot<<<(NN * HID + 255) / 256, 256, 0, stream>>>(hin, WrelL, WrootL, sarr, rarr);
    k_last<<<(NN + 255) / 256, 256, 0, stream>>>(offs, ssrc, ssw, sarr, rarr, brelL, out);
}

// Round 2
// 664.771 us; speedup vs baseline: 5.3570x; 5.3570x over previous
//
#include <hip/hip_runtime.h>

// GraphConv x5 on MI355X — round 2.
// Key restructure vs round 1: middle layers use linearity
//   out = sum_j w_j*(Wrel h_j) + Wroot h_i + b
// so we precompute g = Wrel*h, r = Wroot*h + b (k_pre: VALU-bound, register
// weights + v_readlane broadcasts, no LDS), then aggregation is a pure
// barrier-free gather-accumulate (k_aggrelu: high occupancy, 8 loads in
// flight). CSR built once per call (hist+scan+scatter).

#define NN 100000
#define NE 1600000
#define HID 64
#define SCAN_B 512

__global__ void k_hist(const int* __restrict__ dst, int* __restrict__ counts) {
    int e = blockIdx.x * blockDim.x + threadIdx.x;
    if (e < NE) atomicAdd(&counts[dst[e]], 1);
}

__global__ void k_scan1(const int* __restrict__ counts, int* __restrict__ offs,
                        int* __restrict__ bsums) {
    __shared__ int tmp[SCAN_B];
    int tid = threadIdx.x;
    int i = blockIdx.x * SCAN_B + tid;
    int v = (i < NN) ? counts[i] : 0;
    int acc = v;
    tmp[tid] = v;
    __syncthreads();
    for (int off = 1; off < SCAN_B; off <<= 1) {
        int t = (tid >= off) ? tmp[tid - off] : 0;
        __syncthreads();
        acc += t;
        tmp[tid] = acc;
        __syncthreads();
    }
    if (i < NN) offs[i] = acc - v;
    if (tid == SCAN_B - 1) bsums[blockIdx.x] = acc;
}

__global__ void k_scan2(int* __restrict__ bsums, int nb) {
    __shared__ int tmp[256];
    int tid = threadIdx.x;
    int v = (tid < nb) ? bsums[tid] : 0;
    int acc = v;
    tmp[tid] = v;
    __syncthreads();
    for (int off = 1; off < 256; off <<= 1) {
        int t = (tid >= off) ? tmp[tid - off] : 0;
        __syncthreads();
        acc += t;
        tmp[tid] = acc;
        __syncthreads();
    }
    if (tid < nb) bsums[tid] = acc - v;
}

__global__ void k_scan3(int* __restrict__ offs, const int* __restrict__ bsums,
                        int* __restrict__ cursor) {
    int i = blockIdx.x * blockDim.x + threadIdx.x;
    if (i < NN) {
        int v = offs[i] + bsums[i / SCAN_B];
        offs[i] = v;
        cursor[i] = v;
    }
    if (i == 0) offs[NN] = NE;
}

__global__ void k_scatter(const int* __restrict__ src, const int* __restrict__ dst,
                          const float* __restrict__ w, int* __restrict__ cursor,
                          int* __restrict__ ssrc, float* __restrict__ ssw) {
    int e = blockIdx.x * blockDim.x + threadIdx.x;
    if (e < NE) {
        int d = dst[e];
        int pos = atomicAdd(&cursor[d], 1);
        ssrc[pos] = src[e];
        ssw[pos]  = w[e];
    }
}

__global__ void k_agg_scalar(const int* __restrict__ offs, const int* __restrict__ ssrc,
                             const float* __restrict__ ssw, const float* __restrict__ val,
                             float* __restrict__ out) {
    int i = blockIdx.x * blockDim.x + threadIdx.x;
    if (i >= NN) return;
    float a0 = 0.f, a1 = 0.f;
    int b = offs[i], e = offs[i + 1];
    int j = b;
    for (; j + 2 <= e; j += 2) {
        a0 += ssw[j] * val[ssrc[j]];
        a1 += ssw[j + 1] * val[ssrc[j + 1]];
    }
    for (; j < e; j++) a0 += ssw[j] * val[ssrc[j]];
    out[i] = a0 + a1;
}

__global__ void k_layer0(const float* __restrict__ agg0, const float* __restrict__ x,
                         const float* __restrict__ Wrel0, const float* __restrict__ brel0,
                         const float* __restrict__ Wroot0, float* __restrict__ h) {
    int idx = blockIdx.x * blockDim.x + threadIdx.x;  // NN*64 exact
    int i = idx >> 6, c = idx & 63;
    float v = agg0[i] * Wrel0[c] + brel0[c] + x[i] * Wroot0[c];
    h[idx] = v > 0.f ? v : 0.f;
}

// Per-node dual matvec: g = Wrel*h, r = Wroot*h + b.
// Wave per node (grid-stride). lane = output channel. Weights in registers
// (64+64 VGPRs), h-row broadcast via v_readlane (no LDS pipe, no barriers).
#define PRE_WAVES 3072
__global__ __launch_bounds__(256, 3) void k_pre(
        const float* __restrict__ hin, const float* __restrict__ Wrel,
        const float* __restrict__ brel, const float* __restrict__ Wroot,
        float* __restrict__ G, float* __restrict__ R) {
    int c = threadIdx.x & 63;
    int wid = (blockIdx.x * blockDim.x + threadIdx.x) >> 6;

    float wr[64], wo[64];
    #pragma unroll
    for (int k4 = 0; k4 < 64; k4 += 4) {
        float4 a = *(const float4*)&Wrel[c * 64 + k4];
        float4 b = *(const float4*)&Wroot[c * 64 + k4];
        wr[k4 + 0] = a.x; wr[k4 + 1] = a.y; wr[k4 + 2] = a.z; wr[k4 + 3] = a.w;
        wo[k4 + 0] = b.x; wo[k4 + 1] = b.y; wo[k4 + 2] = b.z; wo[k4 + 3] = b.w;
    }
    float bias = brel[c];

    for (int node = wid; node < NN; node += PRE_WAVES) {
        float hv = hin[node * 64 + c];
        // 8 independent accumulator chains for FMA-latency ILP
        float g0 = 0.f, g1 = 0.f, g2 = 0.f, g3 = 0.f;
        float r0 = 0.f, r1 = 0.f, r2 = 0.f, r3 = 0.f;
        #pragma unroll
        for (int k = 0; k < 64; k += 4) {
            float h0 = __uint_as_float(__builtin_amdgcn_readlane(__float_as_uint(hv), k + 0));
            float h1 = __uint_as_float(__builtin_amdgcn_readlane(__float_as_uint(hv), k + 1));
            float h2 = __uint_as_float(__builtin_amdgcn_readlane(__float_as_uint(hv), k + 2));
            float h3 = __uint_as_float(__builtin_amdgcn_readlane(__float_as_uint(hv), k + 3));
            g0 += h0 * wr[k + 0]; r0 += h0 * wo[k + 0];
            g1 += h1 * wr[k + 1]; r1 += h1 * wo[k + 1];
            g2 += h2 * wr[k + 2]; r2 += h2 * wo[k + 2];
            g3 += h3 * wr[k + 3]; r3 += h3 * wo[k + 3];
        }
        G[node * 64 + c] = (g0 + g1) + (g2 + g3);
        R[node * 64 + c] = ((r0 + r1) + (r2 + r3)) + bias;
    }
}

// Pure gather-accumulate: hout[i][c] = relu( sum_j w_j*G[src_j][c] + R[i][c] )
// Wave per node, lane = channel. No LDS, no barriers; 8 row-loads in flight.
__global__ __launch_bounds__(256) void k_aggrelu(
        const int* __restrict__ offs, const int* __restrict__ ssrc,
        const float* __restrict__ ssw, const float* __restrict__ G,
        const float* __restrict__ R, float* __restrict__ hout) {
    int c = threadIdx.x & 63;
    int node = (blockIdx.x * blockDim.x + threadIdx.x) >> 6;
    if (node >= NN) return;
    int b = offs[node], e = offs[node + 1];
    float a0 = 0.f, a1 = 0.f, a2 = 0.f, a3 = 0.f;
    float a4 = 0.f, a5 = 0.f, a6 = 0.f, a7 = 0.f;
    int j = b;
    for (; j + 8 <= e; j += 8) {
        int s0 = ssrc[j + 0], s1 = ssrc[j + 1], s2 = ssrc[j + 2], s3 = ssrc[j + 3];
        int s4 = ssrc[j + 4], s5 = ssrc[j + 5], s6 = ssrc[j + 6], s7 = ssrc[j + 7];
        float w0 = ssw[j + 0], w1 = ssw[j + 1], w2 = ssw[j + 2], w3 = ssw[j + 3];
        float w4 = ssw[j + 4], w5 = ssw[j + 5], w6 = ssw[j + 6], w7 = ssw[j + 7];
        a0 += w0 * G[s0 * 64 + c]; a1 += w1 * G[s1 * 64 + c];
        a2 += w2 * G[s2 * 64 + c]; a3 += w3 * G[s3 * 64 + c];
        a4 += w4 * G[s4 * 64 + c]; a5 += w5 * G[s5 * 64 + c];
        a6 += w6 * G[s6 * 64 + c]; a7 += w7 * G[s7 * 64 + c];
    }
    for (; j + 4 <= e; j += 4) {
        int s0 = ssrc[j + 0], s1 = ssrc[j + 1], s2 = ssrc[j + 2], s3 = ssrc[j + 3];
        float w0 = ssw[j + 0], w1 = ssw[j + 1], w2 = ssw[j + 2], w3 = ssw[j + 3];
        a0 += w0 * G[s0 * 64 + c]; a1 += w1 * G[s1 * 64 + c];
        a2 += w2 * G[s2 * 64 + c]; a3 += w3 * G[s3 * 64 + c];
    }
    for (; j < e; j++) a0 += ssw[j] * G[ssrc[j] * 64 + c];
    float v = ((a0 + a1) + (a2 + a3)) + ((a4 + a5) + (a6 + a7)) + R[node * 64 + c];
    hout[node * 64 + c] = v > 0.f ? v : 0.f;
}

__global__ void k_lastdot(const float* __restrict__ h, const float* __restrict__ WrelL,
                          const float* __restrict__ WrootL, float* __restrict__ sarr,
                          float* __restrict__ rarr) {
    int g = blockIdx.x * blockDim.x + threadIdx.x;
    int node = g >> 6, lane = g & 63;
    if (node >= NN) return;
    float v = h[node * 64 + lane];
    float a = v * WrelL[lane];
    float c = v * WrootL[lane];
    for (int o = 32; o > 0; o >>= 1) {
        a += __shfl_down(a, o, 64);
        c += __shfl_down(c, o, 64);
    }
    if (lane == 0) { sarr[node] = a; rarr[node] = c; }
}

__global__ void k_last(const int* __restrict__ offs, const int* __restrict__ ssrc,
                       const float* __restrict__ ssw, const float* __restrict__ sarr,
                       const float* __restrict__ rarr, const float* __restrict__ brelL,
                       float* __restrict__ out) {
    int i = blockIdx.x * blockDim.x + threadIdx.x;
    if (i >= NN) return;
    float a0 = rarr[i] + brelL[0], a1 = 0.f;
    int b = offs[i], e = offs[i + 1];
    int j = b;
    for (; j + 2 <= e; j += 2) {
        a0 += ssw[j] * sarr[ssrc[j]];
        a1 += ssw[j + 1] * sarr[ssrc[j + 1]];
    }
    for (; j < e; j++) a0 += ssw[j] * sarr[ssrc[j]];
    out[i] = a0 + a1;
}

extern "C" void kernel_launch(void* const* d_in, const int* in_sizes, int n_in,
                              void* d_out, int out_size, void* d_ws, size_t ws_size,
                              hipStream_t stream) {
    const float* x        = (const float*)d_in[0];
    const int*   ei       = (const int*)d_in[1];
    const float* ew       = (const float*)d_in[2];
    const float* Wrel0    = (const float*)d_in[3];
    const float* brel0    = (const float*)d_in[4];
    const float* Wroot0   = (const float*)d_in[5];
    const float* Wrel_mid = (const float*)d_in[6];
    const float* brel_mid = (const float*)d_in[7];
    const float* Wroot_mid= (const float*)d_in[8];
    const float* WrelL    = (const float*)d_in[9];
    const float* brelL    = (const float*)d_in[10];
    const float* WrootL   = (const float*)d_in[11];
    float* out = (float*)d_out;

    const int* src  = ei;
    const int* dstp = ei + NE;

    char* w = (char*)d_ws;
    size_t o = 0;
    auto alloc = [&](size_t b) -> void* {
        void* r = (void*)(w + o);
        o += (b + 255) & ~(size_t)255;
        return r;
    };
    int*   counts = (int*)alloc((size_t)NN * 4);        // reused as cursor
    int*   offs   = (int*)alloc((size_t)(NN + 1) * 4);
    int*   bsums  = (int*)alloc(256 * 4);
    int*   ssrc   = (int*)alloc((size_t)NE * 4);
    float* ssw    = (float*)alloc((size_t)NE * 4);
    float* H      = (float*)alloc((size_t)NN * HID * 4);
    float* G      = (float*)alloc((size_t)NN * HID * 4);
    float* R      = (float*)alloc((size_t)NN * HID * 4);
    // small scalar buffers alias G's space (G unused at those program points)
    float* agg0 = G;            // used before any mid-layer touches G
    float* sarr = G;            // used after last k_aggrelu consumed G
    float* rarr = G + NN;

    hipMemsetAsync(counts, 0, (size_t)NN * 4, stream);
    int nb1 = (NN + SCAN_B - 1) / SCAN_B;

    k_hist<<<(NE + 255) / 256, 256, 0, stream>>>(dstp, counts);
    k_scan1<<<nb1, SCAN_B, 0, stream>>>(counts, offs, bsums);
    k_scan2<<<1, 256, 0, stream>>>(bsums, nb1);
    k_scan3<<<(NN + 255) / 256, 256, 0, stream>>>(offs, bsums, counts);
    k_scatter<<<(NE + 255) / 256, 256, 0, stream>>>(src, dstp, ew, counts, ssrc, ssw);

    // layer 0 (1-channel input)
    k_agg_scalar<<<(NN + 255) / 256, 256, 0, stream>>>(offs, ssrc, ssw, x, agg0);
    k_layer0<<<(NN * HID) / 256, 256, 0, stream>>>(agg0, x, Wrel0, brel0, Wroot0, H);

    // 3 middle layers: pre-transform then gather-accumulate (H updated in place
    // across kernel boundary; k_pre fully consumes H before k_aggrelu rewrites it)
    for (int l = 0; l < 3; l++) {
        k_pre<<<PRE_WAVES / 4, 256, 0, stream>>>(
            H, Wrel_mid + (size_t)l * HID * HID, brel_mid + (size_t)l * HID,
            Wroot_mid + (size_t)l * HID * HID, G, R);
        k_aggrelu<<<(NN * HID + 255) / 256, 256, 0, stream>>>(offs, ssrc, ssw, G, R, H);
    }

    // last layer: push WrelL through segment_sum -> scalar aggregation
    k_lastdot<<<(NN * HID + 255) / 256, 256, 0, stream>>>(H, WrelL, WrootL, sarr, rarr);
    k_last<<<(NN + 255) / 256, 256, 0, stream>>>(offs, ssrc, ssw, sarr, rarr, brelL, out);
}

// Round 3
// 637.461 us; speedup vs baseline: 5.5866x; 1.0428x over previous
//
#include <hip/hip_runtime.h>

// GraphConv x5 on MI355X — round 3.
// vs round 2: (1) edge metadata packed into one int2 array (single 8B random
// store in scatter; single 8B load stream in aggregation); (2) k_aggrelu uses
// one cooperative 512B metadata load per node + v_readlane broadcasts feeding
// 8 explicitly independent gathers (forced MLP, no remainder divergence).

#define NN 100000
#define NE 1600000
#define HID 64
#define SCAN_B 512

__global__ void k_hist(const int* __restrict__ dst, int* __restrict__ counts) {
    int e = blockIdx.x * blockDim.x + threadIdx.x;
    if (e < NE) atomicAdd(&counts[dst[e]], 1);
}

__global__ void k_scan1(const int* __restrict__ counts, int* __restrict__ offs,
                        int* __restrict__ bsums) {
    __shared__ int tmp[SCAN_B];
    int tid = threadIdx.x;
    int i = blockIdx.x * SCAN_B + tid;
    int v = (i < NN) ? counts[i] : 0;
    int acc = v;
    tmp[tid] = v;
    __syncthreads();
    for (int off = 1; off < SCAN_B; off <<= 1) {
        int t = (tid >= off) ? tmp[tid - off] : 0;
        __syncthreads();
        acc += t;
        tmp[tid] = acc;
        __syncthreads();
    }
    if (i < NN) offs[i] = acc - v;
    if (tid == SCAN_B - 1) bsums[blockIdx.x] = acc;
}

__global__ void k_scan2(int* __restrict__ bsums, int nb) {
    __shared__ int tmp[256];
    int tid = threadIdx.x;
    int v = (tid < nb) ? bsums[tid] : 0;
    int acc = v;
    tmp[tid] = v;
    __syncthreads();
    for (int off = 1; off < 256; off <<= 1) {
        int t = (tid >= off) ? tmp[tid - off] : 0;
        __syncthreads();
        acc += t;
        tmp[tid] = acc;
        __syncthreads();
    }
    if (tid < nb) bsums[tid] = acc - v;
}

__global__ void k_scan3(int* __restrict__ offs, const int* __restrict__ bsums,
                        int* __restrict__ cursor) {
    int i = blockIdx.x * blockDim.x + threadIdx.x;
    if (i < NN) {
        int v = offs[i] + bsums[i / SCAN_B];
        offs[i] = v;
        cursor[i] = v;
    }
    if (i == 0) offs[NN] = NE;
}

// pack (src, weight-bits) into one 8B slot — single random store stream
__global__ void k_scatter(const int* __restrict__ src, const int* __restrict__ dst,
                          const float* __restrict__ w, int* __restrict__ cursor,
                          int2* __restrict__ pairs) {
    int e = blockIdx.x * blockDim.x + threadIdx.x;
    if (e < NE) {
        int d = dst[e];
        int pos = atomicAdd(&cursor[d], 1);
        pairs[pos] = make_int2(src[e], __float_as_int(w[e]));
    }
}

__global__ void k_agg_scalar(const int* __restrict__ offs, const int2* __restrict__ pairs,
                             const float* __restrict__ val, float* __restrict__ out) {
    int i = blockIdx.x * blockDim.x + threadIdx.x;
    if (i >= NN) return;
    float a0 = 0.f, a1 = 0.f;
    int b = offs[i], e = offs[i + 1];
    int j = b;
    for (; j + 2 <= e; j += 2) {
        int2 p0 = pairs[j], p1 = pairs[j + 1];
        a0 += __int_as_float(p0.y) * val[p0.x];
        a1 += __int_as_float(p1.y) * val[p1.x];
    }
    for (; j < e; j++) {
        int2 p = pairs[j];
        a0 += __int_as_float(p.y) * val[p.x];
    }
    out[i] = a0 + a1;
}

__global__ void k_layer0(const float* __restrict__ agg0, const float* __restrict__ x,
                         const float* __restrict__ Wrel0, const float* __restrict__ brel0,
                         const float* __restrict__ Wroot0, float* __restrict__ h) {
    int idx = blockIdx.x * blockDim.x + threadIdx.x;  // NN*64 exact
    int i = idx >> 6, c = idx & 63;
    float v = agg0[i] * Wrel0[c] + brel0[c] + x[i] * Wroot0[c];
    h[idx] = v > 0.f ? v : 0.f;
}

// Per-node dual matvec: g = Wrel*h, r = Wroot*h + b. Wave per node.
#define PRE_WAVES 3072
__global__ __launch_bounds__(256, 3) void k_pre(
        const float* __restrict__ hin, const float* __restrict__ Wrel,
        const float* __restrict__ brel, const float* __restrict__ Wroot,
        float* __restrict__ G, float* __restrict__ R) {
    int c = threadIdx.x & 63;
    int wid = (blockIdx.x * blockDim.x + threadIdx.x) >> 6;

    float wr[64], wo[64];
    #pragma unroll
    for (int k4 = 0; k4 < 64; k4 += 4) {
        float4 a = *(const float4*)&Wrel[c * 64 + k4];
        float4 b = *(const float4*)&Wroot[c * 64 + k4];
        wr[k4 + 0] = a.x; wr[k4 + 1] = a.y; wr[k4 + 2] = a.z; wr[k4 + 3] = a.w;
        wo[k4 + 0] = b.x; wo[k4 + 1] = b.y; wo[k4 + 2] = b.z; wo[k4 + 3] = b.w;
    }
    float bias = brel[c];

    for (int node = wid; node < NN; node += PRE_WAVES) {
        float hv = hin[node * 64 + c];
        float g0 = 0.f, g1 = 0.f, g2 = 0.f, g3 = 0.f;
        float r0 = 0.f, r1 = 0.f, r2 = 0.f, r3 = 0.f;
        #pragma unroll
        for (int k = 0; k < 64; k += 4) {
            float h0 = __uint_as_float(__builtin_amdgcn_readlane(__float_as_uint(hv), k + 0));
            float h1 = __uint_as_float(__builtin_amdgcn_readlane(__float_as_uint(hv), k + 1));
            float h2 = __uint_as_float(__builtin_amdgcn_readlane(__float_as_uint(hv), k + 2));
            float h3 = __uint_as_float(__builtin_amdgcn_readlane(__float_as_uint(hv), k + 3));
            g0 += h0 * wr[k + 0]; r0 += h0 * wo[k + 0];
            g1 += h1 * wr[k + 1]; r1 += h1 * wo[k + 1];
            g2 += h2 * wr[k + 2]; r2 += h2 * wo[k + 2];
            g3 += h3 * wr[k + 3]; r3 += h3 * wo[k + 3];
        }
        G[node * 64 + c] = (g0 + g1) + (g2 + g3);
        R[node * 64 + c] = ((r0 + r1) + (r2 + r3)) + bias;
    }
}

// hout[i][c] = relu( sum_j w_j*G[src_j][c] + R[i][c] )
// Wave per node, lane = channel. One cooperative 8B/lane metadata load per
// 64-edge chunk, v_readlane broadcasts, chunks of 8 independent gathers.
// Lanes beyond degree hold (s=0, w=0): padded chunks gather row 0 with w=0
// (numerically inert, L1-resident) — no remainder divergence.
__global__ __launch_bounds__(256) void k_aggrelu(
        const int* __restrict__ offs, const int2* __restrict__ pairs,
        const float* __restrict__ G, const float* __restrict__ R,
        float* __restrict__ hout) {
    int c = threadIdx.x & 63;
    int node = (blockIdx.x * blockDim.x + threadIdx.x) >> 6;
    if (node >= NN) return;
    int b = offs[node], e = offs[node + 1];
    float a0 = 0.f, a1 = 0.f, a2 = 0.f, a3 = 0.f;
    float a4 = 0.f, a5 = 0.f, a6 = 0.f, a7 = 0.f;
    for (int base = b; base < e; base += 64) {
        int n = e - base; if (n > 64) n = 64;
        int2 p = (c < n) ? pairs[base + c] : make_int2(0, 0);
        int nr = (n + 7) & ~7;
        for (int j = 0; j < nr; j += 8) {
            int s0 = __builtin_amdgcn_readlane(p.x, j + 0);
            int s1 = __builtin_amdgcn_readlane(p.x, j + 1);
            int s2 = __builtin_amdgcn_readlane(p.x, j + 2);
            int s3 = __builtin_amdgcn_readlane(p.x, j + 3);
            int s4 = __builtin_amdgcn_readlane(p.x, j + 4);
            int s5 = __builtin_amdgcn_readlane(p.x, j + 5);
            int s6 = __builtin_amdgcn_readlane(p.x, j + 6);
            int s7 = __builtin_amdgcn_readlane(p.x, j + 7);
            float w0 = __uint_as_float(__builtin_amdgcn_readlane(p.y, j + 0));
            float w1 = __uint_as_float(__builtin_amdgcn_readlane(p.y, j + 1));
            float w2 = __uint_as_float(__builtin_amdgcn_readlane(p.y, j + 2));
            float w3 = __uint_as_float(__builtin_amdgcn_readlane(p.y, j + 3));
            float w4 = __uint_as_float(__builtin_amdgcn_readlane(p.y, j + 4));
            float w5 = __uint_as_float(__builtin_amdgcn_readlane(p.y, j + 5));
            float w6 = __uint_as_float(__builtin_amdgcn_readlane(p.y, j + 6));
            float w7 = __uint_as_float(__builtin_amdgcn_readlane(p.y, j + 7));
            float g0 = G[s0 * 64 + c];
            float g1 = G[s1 * 64 + c];
            float g2 = G[s2 * 64 + c];
            float g3 = G[s3 * 64 + c];
            float g4 = G[s4 * 64 + c];
            float g5 = G[s5 * 64 + c];
            float g6 = G[s6 * 64 + c];
            float g7 = G[s7 * 64 + c];
            a0 += w0 * g0; a1 += w1 * g1; a2 += w2 * g2; a3 += w3 * g3;
            a4 += w4 * g4; a5 += w5 * g5; a6 += w6 * g6; a7 += w7 * g7;
        }
    }
    float v = ((a0 + a1) + (a2 + a3)) + ((a4 + a5) + (a6 + a7)) + R[node * 64 + c];
    hout[node * 64 + c] = v > 0.f ? v : 0.f;
}

__global__ void k_lastdot(const float* __restrict__ h, const float* __restrict__ WrelL,
                          const float* __restrict__ WrootL, float* __restrict__ sarr,
                          float* __restrict__ rarr) {
    int g = blockIdx.x * blockDim.x + threadIdx.x;
    int node = g >> 6, lane = g & 63;
    if (node >= NN) return;
    float v = h[node * 64 + lane];
    float a = v * WrelL[lane];
    float c = v * WrootL[lane];
    for (int o = 32; o > 0; o >>= 1) {
        a += __shfl_down(a, o, 64);
        c += __shfl_down(c, o, 64);
    }
    if (lane == 0) { sarr[node] = a; rarr[node] = c; }
}

__global__ void k_last(const int* __restrict__ offs, const int2* __restrict__ pairs,
                       const float* __restrict__ sarr, const float* __restrict__ rarr,
                       const float* __restrict__ brelL, float* __restrict__ out) {
    int i = blockIdx.x * blockDim.x + threadIdx.x;
    if (i >= NN) return;
    float a0 = rarr[i] + brelL[0], a1 = 0.f;
    int b = offs[i], e = offs[i + 1];
    int j = b;
    for (; j + 2 <= e; j += 2) {
        int2 p0 = pairs[j], p1 = pairs[j + 1];
        a0 += __int_as_float(p0.y) * sarr[p0.x];
        a1 += __int_as_float(p1.y) * sarr[p1.x];
    }
    for (; j < e; j++) {
        int2 p = pairs[j];
        a0 += __int_as_float(p.y) * sarr[p.x];
    }
    out[i] = a0 + a1;
}

extern "C" void kernel_launch(void* const* d_in, const int* in_sizes, int n_in,
                              void* d_out, int out_size, void* d_ws, size_t ws_size,
                              hipStream_t stream) {
    const float* x        = (const float*)d_in[0];
    const int*   ei       = (const int*)d_in[1];
    const float* ew       = (const float*)d_in[2];
    const float* Wrel0    = (const float*)d_in[3];
    const float* brel0    = (const float*)d_in[4];
    const float* Wroot0   = (const float*)d_in[5];
    const float* Wrel_mid = (const float*)d_in[6];
    const float* brel_mid = (const float*)d_in[7];
    const float* Wroot_mid= (const float*)d_in[8];
    const float* WrelL    = (const float*)d_in[9];
    const float* brelL    = (const float*)d_in[10];
    const float* WrootL   = (const float*)d_in[11];
    float* out = (float*)d_out;

    const int* src  = ei;
    const int* dstp = ei + NE;

    char* w = (char*)d_ws;
    size_t o = 0;
    auto alloc = [&](size_t b) -> void* {
        void* r = (void*)(w + o);
        o += (b + 255) & ~(size_t)255;
        return r;
    };
    int*   counts = (int*)alloc((size_t)NN * 4);        // reused as cursor
    int*   offs   = (int*)alloc((size_t)(NN + 1) * 4);
    int*   bsums  = (int*)alloc(256 * 4);
    int2*  pairs  = (int2*)alloc((size_t)NE * 8);
    float* H      = (float*)alloc((size_t)NN * HID * 4);
    float* G      = (float*)alloc((size_t)NN * HID * 4);
    float* R      = (float*)alloc((size_t)NN * HID * 4);
    float* agg0 = G;            // alias: used before any mid-layer touches G
    float* sarr = G;            // alias: used after last k_aggrelu consumed G
    float* rarr = G + NN;

    hipMemsetAsync(counts, 0, (size_t)NN * 4, stream);
    int nb1 = (NN + SCAN_B - 1) / SCAN_B;

    k_hist<<<(NE + 255) / 256, 256, 0, stream>>>(dstp, counts);
    k_scan1<<<nb1, SCAN_B, 0, stream>>>(counts, offs, bsums);
    k_scan2<<<1, 256, 0, stream>>>(bsums, nb1);
    k_scan3<<<(NN + 255) / 256, 256, 0, stream>>>(offs, bsums, counts);
    k_scatter<<<(NE + 255) / 256, 256, 0, stream>>>(src, dstp, ew, counts, pairs);

    // layer 0 (1-channel input)
    k_agg_scalar<<<(NN + 255) / 256, 256, 0, stream>>>(offs, pairs, x, agg0);
    k_layer0<<<(NN * HID) / 256, 256, 0, stream>>>(agg0, x, Wrel0, brel0, Wroot0, H);

    // 3 middle layers
    for (int l = 0; l < 3; l++) {
        k_pre<<<PRE_WAVES / 4, 256, 0, stream>>>(
            H, Wrel_mid + (size_t)l * HID * HID, brel_mid + (size_t)l * HID,
            Wroot_mid + (size_t)l * HID * HID, G, R);
        k_aggrelu<<<(NN * HID + 255) / 256, 256, 0, stream>>>(offs, pairs, G, R, H);
    }

    // last layer: push WrelL through segment_sum -> scalar aggregation
    k_lastdot<<<(NN * HID + 255) / 256, 256, 0, stream>>>(H, WrelL, WrootL, sarr, rarr);
    k_last<<<(NN + 255) / 256, 256, 0, stream>>>(offs, pairs, sarr, rarr, brelL, out);
}

// Round 4
// 583.591 us; speedup vs baseline: 6.1022x; 1.0923x over previous
//
#include <hip/hip_runtime.h>

// GraphConv x5 on MI355X — round 4.
// vs round 3:
// (1) CSR build via 391-bucket radix partition + per-bucket LDS counting
//     sort: all random writes confined to ~32KB L2-local windows (the old
//     global scatter paid a full 64B line writeback per 8B store -> 100MB).
// (2) k_aggrelu processes 4 adjacent nodes per wave: their CSR ranges are
//     contiguous, so one 512B cooperative metadata load covers ~64 edges
//     (vs 16/64 lanes used before); edge->node routing is wave-uniform
//     scalar compares -> zeroed weights (branch-free).

#define NN 100000
#define NE 1600000
#define HID 64
#define NBKT 391            // ceil(NN/256), bucket = dst >> 8

// ---------------- CSR build ----------------

__global__ __launch_bounds__(256) void k_bhist(const int* __restrict__ dst,
                                               int* __restrict__ bcnt) {
    __shared__ int h[NBKT];
    for (int t = threadIdx.x; t < NBKT; t += 256) h[t] = 0;
    __syncthreads();
    int stride = gridDim.x * blockDim.x;
    for (int e = blockIdx.x * blockDim.x + threadIdx.x; e < NE; e += stride)
        atomicAdd(&h[dst[e] >> 8], 1);
    __syncthreads();
    for (int t = threadIdx.x; t < NBKT; t += 256)
        if (h[t]) atomicAdd(&bcnt[t], h[t]);
}

// single block: scan bucket counts -> bases + padded cursors
__global__ void k_bscan(const int* __restrict__ bcnt, int* __restrict__ bbase,
                        int* __restrict__ bcur, int* __restrict__ offs) {
    __shared__ int tmp[512];
    int t = threadIdx.x;
    int v = (t < NBKT) ? bcnt[t] : 0;
    int acc = v;
    tmp[t] = v;
    __syncthreads();
    for (int off = 1; off < 512; off <<= 1) {
        int u = (t >= off) ? tmp[t - off] : 0;
        __syncthreads();
        acc += u;
        tmp[t] = acc;
        __syncthreads();
    }
    if (t < NBKT) {
        bbase[t] = acc - v;
        bcur[t * 16] = acc - v;   // 64B-padded cursor (one line each)
    }
    if (t == 0) { bbase[NBKT] = NE; offs[NN] = NE; }
}

// append-partition: writes within a bucket are dense & monotone -> full lines
__global__ __launch_bounds__(256) void k_bpart(const int* __restrict__ src,
                                               const int* __restrict__ dst,
                                               const float* __restrict__ w,
                                               int* __restrict__ bcur,
                                               int4* __restrict__ bpairs) {
    int stride = gridDim.x * blockDim.x;
    for (int e = blockIdx.x * blockDim.x + threadIdx.x; e < NE; e += stride) {
        int d = dst[e];
        int pos = atomicAdd(&bcur[(d >> 8) * 16], 1);
        bpairs[pos] = make_int4(src[e], __float_as_int(w[e]), d, 0);
    }
}

// one block per bucket: LDS counting sort of ~4100 edges over 256 local dst
__global__ __launch_bounds__(256) void k_bcsr(const int* __restrict__ bbase,
                                              const int4* __restrict__ bpairs,
                                              int* __restrict__ offs,
                                              int2* __restrict__ pairs) {
    __shared__ int cnt[256];
    __shared__ int scn[256];
    __shared__ int cur[256];
    int k = blockIdx.x, t = threadIdx.x;
    int b = bbase[k], e = bbase[k + 1];
    cnt[t] = 0;
    __syncthreads();
    for (int j = b + t; j < e; j += 256)
        atomicAdd(&cnt[bpairs[j].z & 255], 1);
    __syncthreads();
    int v = cnt[t], acc = v;
    scn[t] = v;
    __syncthreads();
    for (int off = 1; off < 256; off <<= 1) {
        int u = (t >= off) ? scn[t - off] : 0;
        __syncthreads();
        acc += u;
        scn[t] = acc;
        __syncthreads();
    }
    int excl = acc - v;
    cur[t] = excl;
    int d = (k << 8) + t;
    if (d < NN) offs[d] = b + excl;
    __syncthreads();
    for (int j = b + t; j < e; j += 256) {
        int4 q = bpairs[j];
        int pos = b + atomicAdd(&cur[q.z & 255], 1);
        pairs[pos] = make_int2(q.x, q.y);   // 8B store, ~32KB L2-local window
    }
}

// ---------------- layers ----------------

__global__ void k_agg_scalar(const int* __restrict__ offs, const int2* __restrict__ pairs,
                             const float* __restrict__ val, float* __restrict__ out) {
    int i = blockIdx.x * blockDim.x + threadIdx.x;
    if (i >= NN) return;
    float a0 = 0.f, a1 = 0.f;
    int b = offs[i], e = offs[i + 1];
    int j = b;
    for (; j + 2 <= e; j += 2) {
        int2 p0 = pairs[j], p1 = pairs[j + 1];
        a0 += __int_as_float(p0.y) * val[p0.x];
        a1 += __int_as_float(p1.y) * val[p1.x];
    }
    for (; j < e; j++) {
        int2 p = pairs[j];
        a0 += __int_as_float(p.y) * val[p.x];
    }
    out[i] = a0 + a1;
}

__global__ void k_layer0(const float* __restrict__ agg0, const float* __restrict__ x,
                         const float* __restrict__ Wrel0, const float* __restrict__ brel0,
                         const float* __restrict__ Wroot0, float* __restrict__ h) {
    int idx = blockIdx.x * blockDim.x + threadIdx.x;  // NN*64 exact
    int i = idx >> 6, c = idx & 63;
    float v = agg0[i] * Wrel0[c] + brel0[c] + x[i] * Wroot0[c];
    h[idx] = v > 0.f ? v : 0.f;
}

// Per-node dual matvec: g = Wrel*h, r = Wroot*h + b. Wave per node.
#define PRE_WAVES 3072
__global__ __launch_bounds__(256, 3) void k_pre(
        const float* __restrict__ hin, const float* __restrict__ Wrel,
        const float* __restrict__ brel, const float* __restrict__ Wroot,
        float* __restrict__ G, float* __restrict__ R) {
    int c = threadIdx.x & 63;
    int wid = (blockIdx.x * blockDim.x + threadIdx.x) >> 6;

    float wr[64], wo[64];
    #pragma unroll
    for (int k4 = 0; k4 < 64; k4 += 4) {
        float4 a = *(const float4*)&Wrel[c * 64 + k4];
        float4 b = *(const float4*)&Wroot[c * 64 + k4];
        wr[k4 + 0] = a.x; wr[k4 + 1] = a.y; wr[k4 + 2] = a.z; wr[k4 + 3] = a.w;
        wo[k4 + 0] = b.x; wo[k4 + 1] = b.y; wo[k4 + 2] = b.z; wo[k4 + 3] = b.w;
    }
    float bias = brel[c];

    for (int node = wid; node < NN; node += PRE_WAVES) {
        float hv = hin[node * 64 + c];
        float g0 = 0.f, g1 = 0.f, g2 = 0.f, g3 = 0.f;
        float r0 = 0.f, r1 = 0.f, r2 = 0.f, r3 = 0.f;
        #pragma unroll
        for (int k = 0; k < 64; k += 4) {
            float h0 = __uint_as_float(__builtin_amdgcn_readlane(__float_as_uint(hv), k + 0));
            float h1 = __uint_as_float(__builtin_amdgcn_readlane(__float_as_uint(hv), k + 1));
            float h2 = __uint_as_float(__builtin_amdgcn_readlane(__float_as_uint(hv), k + 2));
            float h3 = __uint_as_float(__builtin_amdgcn_readlane(__float_as_uint(hv), k + 3));
            g0 += h0 * wr[k + 0]; r0 += h0 * wo[k + 0];
            g1 += h1 * wr[k + 1]; r1 += h1 * wo[k + 1];
            g2 += h2 * wr[k + 2]; r2 += h2 * wo[k + 2];
            g3 += h3 * wr[k + 3]; r3 += h3 * wo[k + 3];
        }
        G[node * 64 + c] = (g0 + g1) + (g2 + g3);
        R[node * 64 + c] = ((r0 + r1) + (r2 + r3)) + bias;
    }
}

// hout[i][c] = relu( sum_j w_j*G[src_j][c] + R[i][c] )
// 4 adjacent nodes per wave: contiguous CSR range [b, e4); one cooperative
// 8B/lane metadata load per 64-edge chunk; edge->node routing via uniform
// scalar compares producing zeroed weights (padded lanes carry w=0).
__global__ __launch_bounds__(256) void k_aggrelu(
        const int* __restrict__ offs, const int2* __restrict__ pairs,
        const float* __restrict__ G, const float* __restrict__ R,
        float* __restrict__ hout) {
    int c = threadIdx.x & 63;
    int wid = (blockIdx.x * blockDim.x + threadIdx.x) >> 6;
    int n0 = wid << 2;                 // NN % 4 == 0
    if (n0 >= NN) return;
    int ov = (c < 5) ? offs[n0 + c] : 0;
    int b  = __builtin_amdgcn_readlane(ov, 0);
    int e1 = __builtin_amdgcn_readlane(ov, 1);
    int e2 = __builtin_amdgcn_readlane(ov, 2);
    int e3 = __builtin_amdgcn_readlane(ov, 3);
    int e4 = __builtin_amdgcn_readlane(ov, 4);

    float a0 = 0.f, a1 = 0.f, a2 = 0.f, a3 = 0.f;
    float a4 = 0.f, a5 = 0.f, a6 = 0.f, a7 = 0.f;

    for (int base = b; base < e4; base += 64) {
        int n = e4 - base; if (n > 64) n = 64;
        int2 p = (c < n) ? pairs[base + c] : make_int2(0, 0);
        int nr = (n + 7) & ~7;
        for (int j = 0; j < nr; j += 8) {
            float g[8];
            #pragma unroll
            for (int t = 0; t < 8; t++) {
                int s = __builtin_amdgcn_readlane(p.x, j + t);
                g[t] = G[s * 64 + c];
            }
            #pragma unroll
            for (int t = 0; t < 8; t++) {
                int gi = base + j + t;
                float wv = __uint_as_float(__builtin_amdgcn_readlane(p.y, j + t));
                float w0 = (gi < e1) ? wv : 0.f;
                float w1 = (gi >= e1 && gi < e2) ? wv : 0.f;
                float w2 = (gi >= e2 && gi < e3) ? wv : 0.f;
                float w3 = (gi >= e3) ? wv : 0.f;   // padded lanes: wv == 0
                if (t & 1) { a4 += w0 * g[t]; a5 += w1 * g[t]; a6 += w2 * g[t]; a7 += w3 * g[t]; }
                else       { a0 += w0 * g[t]; a1 += w1 * g[t]; a2 += w2 * g[t]; a3 += w3 * g[t]; }
            }
        }
    }
    float v0 = a0 + a4 + R[(n0 + 0) * 64 + c];
    float v1 = a1 + a5 + R[(n0 + 1) * 64 + c];
    float v2 = a2 + a6 + R[(n0 + 2) * 64 + c];
    float v3 = a3 + a7 + R[(n0 + 3) * 64 + c];
    hout[(n0 + 0) * 64 + c] = v0 > 0.f ? v0 : 0.f;
    hout[(n0 + 1) * 64 + c] = v1 > 0.f ? v1 : 0.f;
    hout[(n0 + 2) * 64 + c] = v2 > 0.f ? v2 : 0.f;
    hout[(n0 + 3) * 64 + c] = v3 > 0.f ? v3 : 0.f;
}

__global__ void k_lastdot(const float* __restrict__ h, const float* __restrict__ WrelL,
                          const float* __restrict__ WrootL, float* __restrict__ sarr,
                          float* __restrict__ rarr) {
    int g = blockIdx.x * blockDim.x + threadIdx.x;
    int node = g >> 6, lane = g & 63;
    if (node >= NN) return;
    float v = h[node * 64 + lane];
    float a = v * WrelL[lane];
    float c = v * WrootL[lane];
    for (int o = 32; o > 0; o >>= 1) {
        a += __shfl_down(a, o, 64);
        c += __shfl_down(c, o, 64);
    }
    if (lane == 0) { sarr[node] = a; rarr[node] = c; }
}

__global__ void k_last(const int* __restrict__ offs, const int2* __restrict__ pairs,
                       const float* __restrict__ sarr, const float* __restrict__ rarr,
                       const float* __restrict__ brelL, float* __restrict__ out) {
    int i = blockIdx.x * blockDim.x + threadIdx.x;
    if (i >= NN) return;
    float a0 = rarr[i] + brelL[0], a1 = 0.f;
    int b = offs[i], e = offs[i + 1];
    int j = b;
    for (; j + 2 <= e; j += 2) {
        int2 p0 = pairs[j], p1 = pairs[j + 1];
        a0 += __int_as_float(p0.y) * sarr[p0.x];
        a1 += __int_as_float(p1.y) * sarr[p1.x];
    }
    for (; j < e; j++) {
        int2 p = pairs[j];
        a0 += __int_as_float(p.y) * sarr[p.x];
    }
    out[i] = a0 + a1;
}

extern "C" void kernel_launch(void* const* d_in, const int* in_sizes, int n_in,
                              void* d_out, int out_size, void* d_ws, size_t ws_size,
                              hipStream_t stream) {
    const float* x        = (const float*)d_in[0];
    const int*   ei       = (const int*)d_in[1];
    const float* ew       = (const float*)d_in[2];
    const float* Wrel0    = (const float*)d_in[3];
    const float* brel0    = (const float*)d_in[4];
    const float* Wroot0   = (const float*)d_in[5];
    const float* Wrel_mid = (const float*)d_in[6];
    const float* brel_mid = (const float*)d_in[7];
    const float* Wroot_mid= (const float*)d_in[8];
    const float* WrelL    = (const float*)d_in[9];
    const float* brelL    = (const float*)d_in[10];
    const float* WrootL   = (const float*)d_in[11];
    float* out = (float*)d_out;

    const int* src  = ei;
    const int* dstp = ei + NE;

    char* w = (char*)d_ws;
    size_t o = 0;
    auto alloc = [&](size_t b) -> void* {
        void* r = (void*)(w + o);
        o += (b + 255) & ~(size_t)255;
        return r;
    };
    int*   offs   = (int*)alloc((size_t)(NN + 1) * 4);
    int*   bcnt   = (int*)alloc((size_t)NBKT * 4);
    int*   bbase  = (int*)alloc((size_t)(NBKT + 1) * 4);
    int*   bcur   = (int*)alloc((size_t)NBKT * 16 * 4);   // 64B-padded cursors
    int2*  pairs  = (int2*)alloc((size_t)NE * 8);
    float* H      = (float*)alloc((size_t)NN * HID * 4);  // 25.6 MB
    float* G      = (float*)alloc((size_t)NN * HID * 4);
    float* R      = (float*)alloc((size_t)NN * HID * 4);
    // bpairs (NE*16B = 25.6MB) aliases H: dead before k_layer0 writes H
    int4*  bpairs = (int4*)H;
    float* agg0 = G;            // alias: used before any mid-layer touches G
    float* sarr = G;            // alias: used after last k_aggrelu consumed G
    float* rarr = G + NN;

    hipMemsetAsync(bcnt, 0, (size_t)NBKT * 4, stream);

    // CSR build: bucket hist -> scan -> append partition -> per-bucket sort
    k_bhist<<<512, 256, 0, stream>>>(dstp, bcnt);
    k_bscan<<<1, 512, 0, stream>>>(bcnt, bbase, bcur, offs);
    k_bpart<<<1024, 256, 0, stream>>>(src, dstp, ew, bcur, bpairs);
    k_bcsr<<<NBKT, 256, 0, stream>>>(bbase, bpairs, offs, pairs);

    // layer 0 (1-channel input)
    k_agg_scalar<<<(NN + 255) / 256, 256, 0, stream>>>(offs, pairs, x, agg0);
    k_layer0<<<(NN * HID) / 256, 256, 0, stream>>>(agg0, x, Wrel0, brel0, Wroot0, H);

    // 3 middle layers
    for (int l = 0; l < 3; l++) {
        k_pre<<<PRE_WAVES / 4, 256, 0, stream>>>(
            H, Wrel_mid + (size_t)l * HID * HID, brel_mid + (size_t)l * HID,
            Wroot_mid + (size_t)l * HID * HID, G, R);
        k_aggrelu<<<(NN / 4 * 64) / 256, 256, 0, stream>>>(offs, pairs, G, R, H);
    }

    // last layer: push WrelL through segment_sum -> scalar aggregation
    k_lastdot<<<(NN * HID + 255) / 256, 256, 0, stream>>>(H, WrelL, WrootL, sarr, rarr);
    k_last<<<(NN + 255) / 256, 256, 0, stream>>>(offs, pairs, sarr, rarr, brelL, out);
}

// Round 5
// 562.937 us; speedup vs baseline: 6.3261x; 1.0367x over previous
//
#include <hip/hip_runtime.h>
#include <stdint.h>

// GraphConv x5 on MI355X — round 5.
// vs round 4:
// (1) k_bpart: tile-local LDS sort-free partition — per-tile histogram, ONE
//     global atomicAdd per (tile,bucket) segment reservation, then scatter;
//     all writes to a 64B line originate from one block in a tight window so
//     L2 merges them (round-4 bpart paid 95MB writeback vs 25.6 ideal).
//     Edge record packed to int2: (src<<8 | dst&255, w).
// (2) k_pre split into k_preG / k_preR (64 weight VGPRs each — round-4 fused
//     kernel needed 128 and spilled: VGPR_Count=80 < 128 required).
// (3) G stored as bf16 (RNE): halves the 410MB/layer gather traffic in
//     k_aggrelu (128B rows), doubles effective cache hit.

#define NN 100000
#define NE 1600000
#define HID 64
#define NBKT 391            // ceil(NN/256), bucket = dst >> 8
#define TILE 4096
#define EPT 16              // TILE / 256
#define NTILE ((NE + TILE - 1) / TILE)   // 391

// ---------------- CSR build ----------------

__global__ __launch_bounds__(256) void k_bhist(const int* __restrict__ dst,
                                               int* __restrict__ bcnt) {
    __shared__ int h[NBKT];
    for (int t = threadIdx.x; t < NBKT; t += 256) h[t] = 0;
    __syncthreads();
    int stride = gridDim.x * blockDim.x;
    for (int e = blockIdx.x * blockDim.x + threadIdx.x; e < NE; e += stride)
        atomicAdd(&h[dst[e] >> 8], 1);
    __syncthreads();
    for (int t = threadIdx.x; t < NBKT; t += 256)
        if (h[t]) atomicAdd(&bcnt[t], h[t]);
}

// single block: scan bucket counts -> bases + cursors
__global__ void k_bscan(const int* __restrict__ bcnt, int* __restrict__ bbase,
                        int* __restrict__ bcur, int* __restrict__ offs) {
    __shared__ int tmp[512];
    int t = threadIdx.x;
    int v = (t < NBKT) ? bcnt[t] : 0;
    int acc = v;
    tmp[t] = v;
    __syncthreads();
    for (int off = 1; off < 512; off <<= 1) {
        int u = (t >= off) ? tmp[t - off] : 0;
        __syncthreads();
        acc += u;
        tmp[t] = acc;
        __syncthreads();
    }
    if (t < NBKT) {
        bbase[t] = acc - v;
        bcur[t]  = acc - v;
    }
    if (t == 0) { bbase[NBKT] = NE; offs[NN] = NE; }
}

// tile-local partition: one block per 4096-edge tile
__global__ __launch_bounds__(256) void k_bpart(const int* __restrict__ src,
                                               const int* __restrict__ dst,
                                               const float* __restrict__ w,
                                               int* __restrict__ bcur,
                                               int2* __restrict__ bpairs) {
    __shared__ int hcnt[NBKT];
    __shared__ int hbase[NBKT];
    int tile0 = blockIdx.x * TILE;
    for (int t = threadIdx.x; t < NBKT; t += 256) hcnt[t] = 0;
    __syncthreads();

    int   pk[EPT];
    int   bk[EPT];
    float wv[EPT];
    #pragma unroll
    for (int k = 0; k < EPT; k++) {
        int e = tile0 + threadIdx.x + k * 256;
        if (e < NE) {
            int d = dst[e];
            int b = d >> 8;
            pk[k] = (src[e] << 8) | (d & 255);
            wv[k] = w[e];
            bk[k] = b;
            atomicAdd(&hcnt[b], 1);
        } else {
            bk[k] = -1;
        }
    }
    __syncthreads();
    for (int t = threadIdx.x; t < NBKT; t += 256) {
        int c = hcnt[t];
        hbase[t] = c ? atomicAdd(&bcur[t], c) : 0;   // one global atomic per seg
        hcnt[t] = 0;                                  // reuse as local cursor
    }
    __syncthreads();
    #pragma unroll
    for (int k = 0; k < EPT; k++) {
        if (bk[k] >= 0) {
            int pos = hbase[bk[k]] + atomicAdd(&hcnt[bk[k]], 1);
            bpairs[pos] = make_int2(pk[k], __float_as_int(wv[k]));
        }
    }
}

// one block per bucket: LDS counting sort of ~4100 edges over 256 local dst
__global__ __launch_bounds__(256) void k_bcsr(const int* __restrict__ bbase,
                                              const int2* __restrict__ bpairs,
                                              int* __restrict__ offs,
                                              int2* __restrict__ pairs) {
    __shared__ int cnt[256];
    __shared__ int scn[256];
    __shared__ int cur[256];
    int k = blockIdx.x, t = threadIdx.x;
    int b = bbase[k], e = bbase[k + 1];
    cnt[t] = 0;
    __syncthreads();
    for (int j = b + t; j < e; j += 256)
        atomicAdd(&cnt[bpairs[j].x & 255], 1);
    __syncthreads();
    int v = cnt[t], acc = v;
    scn[t] = v;
    __syncthreads();
    for (int off = 1; off < 256; off <<= 1) {
        int u = (t >= off) ? scn[t - off] : 0;
        __syncthreads();
        acc += u;
        scn[t] = acc;
        __syncthreads();
    }
    int excl = acc - v;
    cur[t] = excl;
    int d = (k << 8) + t;
    if (d < NN) offs[d] = b + excl;
    __syncthreads();
    for (int j = b + t; j < e; j += 256) {
        int2 q = bpairs[j];
        int pos = b + atomicAdd(&cur[q.x & 255], 1);
        pairs[pos] = make_int2(q.x >> 8, q.y);  // 8B store, ~32KB-local window
    }
}

// ---------------- layers ----------------

__global__ void k_agg_scalar(const int* __restrict__ offs, const int2* __restrict__ pairs,
                             const float* __restrict__ val, float* __restrict__ out) {
    int i = blockIdx.x * blockDim.x + threadIdx.x;
    if (i >= NN) return;
    float a0 = 0.f, a1 = 0.f;
    int b = offs[i], e = offs[i + 1];
    int j = b;
    for (; j + 2 <= e; j += 2) {
        int2 p0 = pairs[j], p1 = pairs[j + 1];
        a0 += __int_as_float(p0.y) * val[p0.x];
        a1 += __int_as_float(p1.y) * val[p1.x];
    }
    for (; j < e; j++) {
        int2 p = pairs[j];
        a0 += __int_as_float(p.y) * val[p.x];
    }
    out[i] = a0 + a1;
}

__global__ void k_layer0(const float* __restrict__ agg0, const float* __restrict__ x,
                         const float* __restrict__ Wrel0, const float* __restrict__ brel0,
                         const float* __restrict__ Wroot0, float* __restrict__ h) {
    int idx = blockIdx.x * blockDim.x + threadIdx.x;  // NN*64 exact
    int i = idx >> 6, c = idx & 63;
    float v = agg0[i] * Wrel0[c] + brel0[c] + x[i] * Wroot0[c];
    h[idx] = v > 0.f ? v : 0.f;
}

#define PRE_WAVES 4096

// G[i] = Wrel * h[i], stored bf16 (RNE). Wave per node, lane = out channel,
// 64 weight VGPRs (no spill), h-row broadcast via readlane.
__global__ __launch_bounds__(256) void k_preG(
        const float* __restrict__ hin, const float* __restrict__ Wrel,
        uint16_t* __restrict__ Gb) {
    int c = threadIdx.x & 63;
    int wid = (blockIdx.x * blockDim.x + threadIdx.x) >> 6;
    float wr[64];
    #pragma unroll
    for (int k4 = 0; k4 < 64; k4 += 4) {
        float4 a = *(const float4*)&Wrel[c * 64 + k4];
        wr[k4 + 0] = a.x; wr[k4 + 1] = a.y; wr[k4 + 2] = a.z; wr[k4 + 3] = a.w;
    }
    for (int node = wid; node < NN; node += PRE_WAVES) {
        float hv = hin[node * 64 + c];
        float g0 = 0.f, g1 = 0.f, g2 = 0.f, g3 = 0.f;
        #pragma unroll
        for (int k = 0; k < 64; k += 4) {
            g0 += __uint_as_float(__builtin_amdgcn_readlane(__float_as_uint(hv), k + 0)) * wr[k + 0];
            g1 += __uint_as_float(__builtin_amdgcn_readlane(__float_as_uint(hv), k + 1)) * wr[k + 1];
            g2 += __uint_as_float(__builtin_amdgcn_readlane(__float_as_uint(hv), k + 2)) * wr[k + 2];
            g3 += __uint_as_float(__builtin_amdgcn_readlane(__float_as_uint(hv), k + 3)) * wr[k + 3];
        }
        float g = (g0 + g1) + (g2 + g3);
        uint32_t bits = __float_as_uint(g);
        uint32_t r = (bits + 0x7fffu + ((bits >> 16) & 1u)) >> 16;   // RNE
        Gb[node * 64 + c] = (uint16_t)r;
    }
}

// R[i] = Wroot * h[i] + b, fp32.
__global__ __launch_bounds__(256) void k_preR(
        const float* __restrict__ hin, const float* __restrict__ Wroot,
        const float* __restrict__ brel, float* __restrict__ R) {
    int c = threadIdx.x & 63;
    int wid = (blockIdx.x * blockDim.x + threadIdx.x) >> 6;
    float wo[64];
    #pragma unroll
    for (int k4 = 0; k4 < 64; k4 += 4) {
        float4 a = *(const float4*)&Wroot[c * 64 + k4];
        wo[k4 + 0] = a.x; wo[k4 + 1] = a.y; wo[k4 + 2] = a.z; wo[k4 + 3] = a.w;
    }
    float bias = brel[c];
    for (int node = wid; node < NN; node += PRE_WAVES) {
        float hv = hin[node * 64 + c];
        float r0 = 0.f, r1 = 0.f, r2 = 0.f, r3 = 0.f;
        #pragma unroll
        for (int k = 0; k < 64; k += 4) {
            r0 += __uint_as_float(__builtin_amdgcn_readlane(__float_as_uint(hv), k + 0)) * wo[k + 0];
            r1 += __uint_as_float(__builtin_amdgcn_readlane(__float_as_uint(hv), k + 1)) * wo[k + 1];
            r2 += __uint_as_float(__builtin_amdgcn_readlane(__float_as_uint(hv), k + 2)) * wo[k + 2];
            r3 += __uint_as_float(__builtin_amdgcn_readlane(__float_as_uint(hv), k + 3)) * wo[k + 3];
        }
        R[node * 64 + c] = ((r0 + r1) + (r2 + r3)) + bias;
    }
}

// hout[i][c] = relu( sum_j w_j*G[src_j][c] + R[i][c] ), G in bf16 (128B rows).
// 4 adjacent nodes per wave (contiguous CSR range), cooperative 8B/lane
// metadata loads, readlane broadcasts, 8 independent gathers in flight.
__global__ __launch_bounds__(256) void k_aggrelu(
        const int* __restrict__ offs, const int2* __restrict__ pairs,
        const uint32_t* __restrict__ Gb, const float* __restrict__ R,
        float* __restrict__ hout) {
    int c = threadIdx.x & 63;
    int half = c >> 1;
    int sh = (c & 1) ? 0 : 16;        // g = as_float((u << sh) & 0xffff0000)
    int wid = (blockIdx.x * blockDim.x + threadIdx.x) >> 6;
    int n0 = wid << 2;                // NN % 4 == 0
    if (n0 >= NN) return;
    int ov = (c < 5) ? offs[n0 + c] : 0;
    int b  = __builtin_amdgcn_readlane(ov, 0);
    int e1 = __builtin_amdgcn_readlane(ov, 1);
    int e2 = __builtin_amdgcn_readlane(ov, 2);
    int e3 = __builtin_amdgcn_readlane(ov, 3);
    int e4 = __builtin_amdgcn_readlane(ov, 4);

    float a0 = 0.f, a1 = 0.f, a2 = 0.f, a3 = 0.f;
    float a4 = 0.f, a5 = 0.f, a6 = 0.f, a7 = 0.f;

    for (int base = b; base < e4; base += 64) {
        int n = e4 - base; if (n > 64) n = 64;
        int2 p = (c < n) ? pairs[base + c] : make_int2(0, 0);
        int nr = (n + 7) & ~7;
        for (int j = 0; j < nr; j += 8) {
            float g[8];
            #pragma unroll
            for (int t = 0; t < 8; t++) {
                int s = __builtin_amdgcn_readlane(p.x, j + t);
                uint32_t u = Gb[s * 32 + half];
                g[t] = __uint_as_float((u << sh) & 0xffff0000u);
            }
            #pragma unroll
            for (int t = 0; t < 8; t++) {
                int gi = base + j + t;
                float wv = __uint_as_float(__builtin_amdgcn_readlane(p.y, j + t));
                float w0 = (gi < e1) ? wv : 0.f;
                float w1 = (gi >= e1 && gi < e2) ? wv : 0.f;
                float w2 = (gi >= e2 && gi < e3) ? wv : 0.f;
                float w3 = (gi >= e3) ? wv : 0.f;   // padded lanes: wv == 0
                if (t & 1) { a4 += w0 * g[t]; a5 += w1 * g[t]; a6 += w2 * g[t]; a7 += w3 * g[t]; }
                else       { a0 += w0 * g[t]; a1 += w1 * g[t]; a2 += w2 * g[t]; a3 += w3 * g[t]; }
            }
        }
    }
    float v0 = a0 + a4 + R[(n0 + 0) * 64 + c];
    float v1 = a1 + a5 + R[(n0 + 1) * 64 + c];
    float v2 = a2 + a6 + R[(n0 + 2) * 64 + c];
    float v3 = a3 + a7 + R[(n0 + 3) * 64 + c];
    hout[(n0 + 0) * 64 + c] = v0 > 0.f ? v0 : 0.f;
    hout[(n0 + 1) * 64 + c] = v1 > 0.f ? v1 : 0.f;
    hout[(n0 + 2) * 64 + c] = v2 > 0.f ? v2 : 0.f;
    hout[(n0 + 3) * 64 + c] = v3 > 0.f ? v3 : 0.f;
}

__global__ void k_lastdot(const float* __restrict__ h, const float* __restrict__ WrelL,
                          const float* __restrict__ WrootL, float* __restrict__ sarr,
                          float* __restrict__ rarr) {
    int g = blockIdx.x * blockDim.x + threadIdx.x;
    int node = g >> 6, lane = g & 63;
    if (node >= NN) return;
    float v = h[node * 64 + lane];
    float a = v * WrelL[lane];
    float c = v * WrootL[lane];
    for (int o = 32; o > 0; o >>= 1) {
        a += __shfl_down(a, o, 64);
        c += __shfl_down(c, o, 64);
    }
    if (lane == 0) { sarr[node] = a; rarr[node] = c; }
}

__global__ void k_last(const int* __restrict__ offs, const int2* __restrict__ pairs,
                       const float* __restrict__ sarr, const float* __restrict__ rarr,
                       const float* __restrict__ brelL, float* __restrict__ out) {
    int i = blockIdx.x * blockDim.x + threadIdx.x;
    if (i >= NN) return;
    float a0 = rarr[i] + brelL[0], a1 = 0.f;
    int b = offs[i], e = offs[i + 1];
    int j = b;
    for (; j + 2 <= e; j += 2) {
        int2 p0 = pairs[j], p1 = pairs[j + 1];
        a0 += __int_as_float(p0.y) * sarr[p0.x];
        a1 += __int_as_float(p1.y) * sarr[p1.x];
    }
    for (; j < e; j++) {
        int2 p = pairs[j];
        a0 += __int_as_float(p.y) * sarr[p.x];
    }
    out[i] = a0 + a1;
}

extern "C" void kernel_launch(void* const* d_in, const int* in_sizes, int n_in,
                              void* d_out, int out_size, void* d_ws, size_t ws_size,
                              hipStream_t stream) {
    const float* x        = (const float*)d_in[0];
    const int*   ei       = (const int*)d_in[1];
    const float* ew       = (const float*)d_in[2];
    const float* Wrel0    = (const float*)d_in[3];
    const float* brel0    = (const float*)d_in[4];
    const float* Wroot0   = (const float*)d_in[5];
    const float* Wrel_mid = (const float*)d_in[6];
    const float* brel_mid = (const float*)d_in[7];
    const float* Wroot_mid= (const float*)d_in[8];
    const float* WrelL    = (const float*)d_in[9];
    const float* brelL    = (const float*)d_in[10];
    const float* WrootL   = (const float*)d_in[11];
    float* out = (float*)d_out;

    const int* src  = ei;
    const int* dstp = ei + NE;

    char* w = (char*)d_ws;
    size_t o = 0;
    auto alloc = [&](size_t b) -> void* {
        void* r = (void*)(w + o);
        o += (b + 255) & ~(size_t)255;
        return r;
    };
    int*      offs  = (int*)alloc((size_t)(NN + 1) * 4);
    int*      bcnt  = (int*)alloc((size_t)NBKT * 4);
    int*      bbase = (int*)alloc((size_t)(NBKT + 1) * 4);
    int*      bcur  = (int*)alloc((size_t)NBKT * 4);
    int2*     pairs = (int2*)alloc((size_t)NE * 8);
    float*    H     = (float*)alloc((size_t)NN * HID * 4);   // 25.6 MB
    uint16_t* Gb    = (uint16_t*)alloc((size_t)NN * HID * 2);// 12.8 MB
    float*    R     = (float*)alloc((size_t)NN * HID * 4);   // 25.6 MB
    // bpairs (NE*8B = 12.8MB) aliases H: dead before k_layer0 writes H
    int2*  bpairs = (int2*)H;
    // scalar aliases into Gb region (dead at those program points)
    float* agg0 = (float*)Gb;          // used before first k_preG
    float* sarr = (float*)Gb;          // used after last k_aggrelu consumed Gb
    float* rarr = (float*)Gb + NN;

    hipMemsetAsync(bcnt, 0, (size_t)NBKT * 4, stream);

    // CSR build
    k_bhist<<<512, 256, 0, stream>>>(dstp, bcnt);
    k_bscan<<<1, 512, 0, stream>>>(bcnt, bbase, bcur, offs);
    k_bpart<<<NTILE, 256, 0, stream>>>(src, dstp, ew, bcur, bpairs);
    k_bcsr<<<NBKT, 256, 0, stream>>>(bbase, bpairs, offs, pairs);

    // layer 0 (1-channel input)
    k_agg_scalar<<<(NN + 255) / 256, 256, 0, stream>>>(offs, pairs, x, agg0);
    k_layer0<<<(NN * HID) / 256, 256, 0, stream>>>(agg0, x, Wrel0, brel0, Wroot0, H);

    // 3 middle layers
    for (int l = 0; l < 3; l++) {
        k_preG<<<PRE_WAVES / 4, 256, 0, stream>>>(
            H, Wrel_mid + (size_t)l * HID * HID, Gb);
        k_preR<<<PRE_WAVES / 4, 256, 0, stream>>>(
            H, Wroot_mid + (size_t)l * HID * HID, brel_mid + (size_t)l * HID, R);
        k_aggrelu<<<(NN / 4 * 64) / 256, 256, 0, stream>>>(
            offs, pairs, (const uint32_t*)Gb, R, H);
    }

    // last layer: push WrelL through segment_sum -> scalar aggregation
    k_lastdot<<<(NN * HID + 255) / 256, 256, 0, stream>>>(H, WrelL, WrootL, sarr, rarr);
    k_last<<<(NN + 255) / 256, 256, 0, stream>>>(offs, pairs, sarr, rarr, brelL, out);
}

// Round 6
// 517.783 us; speedup vs baseline: 6.8778x; 1.0872x over previous
//
#include <hip/hip_runtime.h>
#include <stdint.h>

// GraphConv x5 on MI355X — round 6.
// vs round 5:
// (1) k_aggrelu: per-node scalar-bound segmented loops inside the cooperative
//     64-edge window — removes the 4-way masked-FMA routing (4 fma + 8 sel
//     per edge -> 1 fma), the round-5 kernel was VALU-bound at 80% busy.
//     Inner loop unrolled x4, dual accumulator chains, 4 gathers in flight.
// (2) k_preG/k_preR fused into one launch (block-uniform role), G and R run
//     concurrently; 3 fewer launches.

#define NN 100000
#define NE 1600000
#define HID 64
#define NBKT 391            // ceil(NN/256), bucket = dst >> 8
#define TILE 4096
#define EPT 16              // TILE / 256
#define NTILE ((NE + TILE - 1) / TILE)   // 391

// ---------------- CSR build ----------------

__global__ __launch_bounds__(256) void k_bhist(const int* __restrict__ dst,
                                               int* __restrict__ bcnt) {
    __shared__ int h[NBKT];
    for (int t = threadIdx.x; t < NBKT; t += 256) h[t] = 0;
    __syncthreads();
    int stride = gridDim.x * blockDim.x;
    for (int e = blockIdx.x * blockDim.x + threadIdx.x; e < NE; e += stride)
        atomicAdd(&h[dst[e] >> 8], 1);
    __syncthreads();
    for (int t = threadIdx.x; t < NBKT; t += 256)
        if (h[t]) atomicAdd(&bcnt[t], h[t]);
}

__global__ void k_bscan(const int* __restrict__ bcnt, int* __restrict__ bbase,
                        int* __restrict__ bcur, int* __restrict__ offs) {
    __shared__ int tmp[512];
    int t = threadIdx.x;
    int v = (t < NBKT) ? bcnt[t] : 0;
    int acc = v;
    tmp[t] = v;
    __syncthreads();
    for (int off = 1; off < 512; off <<= 1) {
        int u = (t >= off) ? tmp[t - off] : 0;
        __syncthreads();
        acc += u;
        tmp[t] = acc;
        __syncthreads();
    }
    if (t < NBKT) {
        bbase[t] = acc - v;
        bcur[t]  = acc - v;
    }
    if (t == 0) { bbase[NBKT] = NE; offs[NN] = NE; }
}

// tile-local partition: one block per 4096-edge tile
__global__ __launch_bounds__(256) void k_bpart(const int* __restrict__ src,
                                               const int* __restrict__ dst,
                                               const float* __restrict__ w,
                                               int* __restrict__ bcur,
                                               int2* __restrict__ bpairs) {
    __shared__ int hcnt[NBKT];
    __shared__ int hbase[NBKT];
    int tile0 = blockIdx.x * TILE;
    for (int t = threadIdx.x; t < NBKT; t += 256) hcnt[t] = 0;
    __syncthreads();

    int   pk[EPT];
    int   bk[EPT];
    float wv[EPT];
    #pragma unroll
    for (int k = 0; k < EPT; k++) {
        int e = tile0 + threadIdx.x + k * 256;
        if (e < NE) {
            int d = dst[e];
            int b = d >> 8;
            pk[k] = (src[e] << 8) | (d & 255);
            wv[k] = w[e];
            bk[k] = b;
            atomicAdd(&hcnt[b], 1);
        } else {
            bk[k] = -1;
        }
    }
    __syncthreads();
    for (int t = threadIdx.x; t < NBKT; t += 256) {
        int c = hcnt[t];
        hbase[t] = c ? atomicAdd(&bcur[t], c) : 0;
        hcnt[t] = 0;
    }
    __syncthreads();
    #pragma unroll
    for (int k = 0; k < EPT; k++) {
        if (bk[k] >= 0) {
            int pos = hbase[bk[k]] + atomicAdd(&hcnt[bk[k]], 1);
            bpairs[pos] = make_int2(pk[k], __float_as_int(wv[k]));
        }
    }
}

// one block per bucket: LDS counting sort over 256 local dst
__global__ __launch_bounds__(256) void k_bcsr(const int* __restrict__ bbase,
                                              const int2* __restrict__ bpairs,
                                              int* __restrict__ offs,
                                              int2* __restrict__ pairs) {
    __shared__ int cnt[256];
    __shared__ int scn[256];
    __shared__ int cur[256];
    int k = blockIdx.x, t = threadIdx.x;
    int b = bbase[k], e = bbase[k + 1];
    cnt[t] = 0;
    __syncthreads();
    for (int j = b + t; j < e; j += 256)
        atomicAdd(&cnt[bpairs[j].x & 255], 1);
    __syncthreads();
    int v = cnt[t], acc = v;
    scn[t] = v;
    __syncthreads();
    for (int off = 1; off < 256; off <<= 1) {
        int u = (t >= off) ? scn[t - off] : 0;
        __syncthreads();
        acc += u;
        scn[t] = acc;
        __syncthreads();
    }
    int excl = acc - v;
    cur[t] = excl;
    int d = (k << 8) + t;
    if (d < NN) offs[d] = b + excl;
    __syncthreads();
    for (int j = b + t; j < e; j += 256) {
        int2 q = bpairs[j];
        int pos = b + atomicAdd(&cur[q.x & 255], 1);
        pairs[pos] = make_int2(q.x >> 8, q.y);
    }
}

// ---------------- layers ----------------

__global__ void k_agg_scalar(const int* __restrict__ offs, const int2* __restrict__ pairs,
                             const float* __restrict__ val, float* __restrict__ out) {
    int i = blockIdx.x * blockDim.x + threadIdx.x;
    if (i >= NN) return;
    float a0 = 0.f, a1 = 0.f;
    int b = offs[i], e = offs[i + 1];
    int j = b;
    for (; j + 2 <= e; j += 2) {
        int2 p0 = pairs[j], p1 = pairs[j + 1];
        a0 += __int_as_float(p0.y) * val[p0.x];
        a1 += __int_as_float(p1.y) * val[p1.x];
    }
    for (; j < e; j++) {
        int2 p = pairs[j];
        a0 += __int_as_float(p.y) * val[p.x];
    }
    out[i] = a0 + a1;
}

__global__ void k_layer0(const float* __restrict__ agg0, const float* __restrict__ x,
                         const float* __restrict__ Wrel0, const float* __restrict__ brel0,
                         const float* __restrict__ Wroot0, float* __restrict__ h) {
    int idx = blockIdx.x * blockDim.x + threadIdx.x;  // NN*64 exact
    int i = idx >> 6, c = idx & 63;
    float v = agg0[i] * Wrel0[c] + brel0[c] + x[i] * Wroot0[c];
    h[idx] = v > 0.f ? v : 0.f;
}

#define PREB 1024           // blocks per role; 4096 waves
#define PRE_WAVES 4096

// Fused pre-transform. Blocks [0,PREB): G = bf16(Wrel*h). Blocks [PREB,2*PREB):
// R = Wroot*h + b (fp32). Block-uniform role -> no divergence; 64 weight VGPRs.
__global__ __launch_bounds__(256) void k_pre2(
        const float* __restrict__ hin, const float* __restrict__ Wrel,
        const float* __restrict__ Wroot, const float* __restrict__ brel,
        uint16_t* __restrict__ Gb, float* __restrict__ R) {
    bool doR = blockIdx.x >= PREB;
    int bid = doR ? (blockIdx.x - PREB) : blockIdx.x;
    int c = threadIdx.x & 63;
    int wid = (bid * 256 + (int)threadIdx.x) >> 6;
    const float* W = doR ? Wroot : Wrel;
    float wk[64];
    #pragma unroll
    for (int k4 = 0; k4 < 64; k4 += 4) {
        float4 a = *(const float4*)&W[c * 64 + k4];
        wk[k4 + 0] = a.x; wk[k4 + 1] = a.y; wk[k4 + 2] = a.z; wk[k4 + 3] = a.w;
    }
    float bias = doR ? brel[c] : 0.f;

    for (int node = wid; node < NN; node += PRE_WAVES) {
        float hv = hin[node * 64 + c];
        float g0 = 0.f, g1 = 0.f, g2 = 0.f, g3 = 0.f;
        #pragma unroll
        for (int k = 0; k < 64; k += 4) {
            g0 += __uint_as_float(__builtin_amdgcn_readlane(__float_as_uint(hv), k + 0)) * wk[k + 0];
            g1 += __uint_as_float(__builtin_amdgcn_readlane(__float_as_uint(hv), k + 1)) * wk[k + 1];
            g2 += __uint_as_float(__builtin_amdgcn_readlane(__float_as_uint(hv), k + 2)) * wk[k + 2];
            g3 += __uint_as_float(__builtin_amdgcn_readlane(__float_as_uint(hv), k + 3)) * wk[k + 3];
        }
        float g = (g0 + g1) + (g2 + g3);
        if (doR) {
            R[node * 64 + c] = g + bias;
        } else {
            uint32_t bits = __float_as_uint(g);
            uint32_t r = (bits + 0x7fffu + ((bits >> 16) & 1u)) >> 16;   // RNE
            Gb[node * 64 + c] = (uint16_t)r;
        }
    }
}

// hout[i][c] = relu( sum_j w_j*G[src_j][c] + R[i][c] ), G bf16 (128B rows).
// 4 adjacent nodes per wave; cooperative 64-edge metadata window; per-node
// SCALAR-bound segmented loops (no masked FMAs) — exactly 1 fmac per edge.
__global__ __launch_bounds__(256) void k_aggrelu(
        const int* __restrict__ offs, const int2* __restrict__ pairs,
        const uint32_t* __restrict__ Gb, const float* __restrict__ R,
        float* __restrict__ hout) {
    int c = threadIdx.x & 63;
    int half = c >> 1;
    int sh = (c & 1) ? 0 : 16;        // g = as_float((u << sh) & 0xffff0000)
    int wid = (blockIdx.x * blockDim.x + threadIdx.x) >> 6;
    int n0 = wid << 2;                // NN % 4 == 0
    if (n0 >= NN) return;
    int ov = (c < 5) ? offs[n0 + c] : 0;
    int bnd[5];
    bnd[0] = __builtin_amdgcn_readlane(ov, 0);
    bnd[1] = __builtin_amdgcn_readlane(ov, 1);
    bnd[2] = __builtin_amdgcn_readlane(ov, 2);
    bnd[3] = __builtin_amdgcn_readlane(ov, 3);
    bnd[4] = __builtin_amdgcn_readlane(ov, 4);

    float accA[4] = {0.f, 0.f, 0.f, 0.f};
    float accB[4] = {0.f, 0.f, 0.f, 0.f};

    for (int cb = bnd[0]; cb < bnd[4]; cb += 64) {
        int n = bnd[4] - cb; if (n > 64) n = 64;
        int2 p = (c < n) ? pairs[cb + c] : make_int2(0, 0);
        #pragma unroll
        for (int t = 0; t < 4; t++) {
            int lo = bnd[t]     > cb     ? bnd[t]     : cb;
            int hi = bnd[t + 1] < cb + n ? bnd[t + 1] : cb + n;
            int j = lo;
            for (; j + 4 <= hi; j += 4) {
                int jj = j - cb;
                int s0 = __builtin_amdgcn_readlane(p.x, jj + 0);
                int s1 = __builtin_amdgcn_readlane(p.x, jj + 1);
                int s2 = __builtin_amdgcn_readlane(p.x, jj + 2);
                int s3 = __builtin_amdgcn_readlane(p.x, jj + 3);
                float w0 = __uint_as_float(__builtin_amdgcn_readlane(p.y, jj + 0));
                float w1 = __uint_as_float(__builtin_amdgcn_readlane(p.y, jj + 1));
                float w2 = __uint_as_float(__builtin_amdgcn_readlane(p.y, jj + 2));
                float w3 = __uint_as_float(__builtin_amdgcn_readlane(p.y, jj + 3));
                uint32_t u0 = Gb[s0 * 32 + half];
                uint32_t u1 = Gb[s1 * 32 + half];
                uint32_t u2 = Gb[s2 * 32 + half];
                uint32_t u3 = Gb[s3 * 32 + half];
                float g0 = __uint_as_float((u0 << sh) & 0xffff0000u);
                float g1 = __uint_as_float((u1 << sh) & 0xffff0000u);
                float g2 = __uint_as_float((u2 << sh) & 0xffff0000u);
                float g3 = __uint_as_float((u3 << sh) & 0xffff0000u);
                accA[t] += w0 * g0;
                accB[t] += w1 * g1;
                accA[t] += w2 * g2;
                accB[t] += w3 * g3;
            }
            for (; j < hi; j++) {
                int jj = j - cb;
                int s = __builtin_amdgcn_readlane(p.x, jj);
                float wv = __uint_as_float(__builtin_amdgcn_readlane(p.y, jj));
                uint32_t u = Gb[s * 32 + half];
                accA[t] += wv * __uint_as_float((u << sh) & 0xffff0000u);
            }
        }
    }
    #pragma unroll
    for (int t = 0; t < 4; t++) {
        float v = accA[t] + accB[t] + R[(n0 + t) * 64 + c];
        hout[(n0 + t) * 64 + c] = v > 0.f ? v : 0.f;
    }
}

__global__ void k_lastdot(const float* __restrict__ h, const float* __restrict__ WrelL,
                          const float* __restrict__ WrootL, float* __restrict__ sarr,
                          float* __restrict__ rarr) {
    int g = blockIdx.x * blockDim.x + threadIdx.x;
    int node = g >> 6, lane = g & 63;
    if (node >= NN) return;
    float v = h[node * 64 + lane];
    float a = v * WrelL[lane];
    float c = v * WrootL[lane];
    for (int o = 32; o > 0; o >>= 1) {
        a += __shfl_down(a, o, 64);
        c += __shfl_down(c, o, 64);
    }
    if (lane == 0) { sarr[node] = a; rarr[node] = c; }
}

__global__ void k_last(const int* __restrict__ offs, const int2* __restrict__ pairs,
                       const float* __restrict__ sarr, const float* __restrict__ rarr,
                       const float* __restrict__ brelL, float* __restrict__ out) {
    int i = blockIdx.x * blockDim.x + threadIdx.x;
    if (i >= NN) return;
    float a0 = rarr[i] + brelL[0], a1 = 0.f;
    int b = offs[i], e = offs[i + 1];
    int j = b;
    for (; j + 2 <= e; j += 2) {
        int2 p0 = pairs[j], p1 = pairs[j + 1];
        a0 += __int_as_float(p0.y) * sarr[p0.x];
        a1 += __int_as_float(p1.y) * sarr[p1.x];
    }
    for (; j < e; j++) {
        int2 p = pairs[j];
        a0 += __int_as_float(p.y) * sarr[p.x];
    }
    out[i] = a0 + a1;
}

extern "C" void kernel_launch(void* const* d_in, const int* in_sizes, int n_in,
                              void* d_out, int out_size, void* d_ws, size_t ws_size,
                              hipStream_t stream) {
    const float* x        = (const float*)d_in[0];
    const int*   ei       = (const int*)d_in[1];
    const float* ew       = (const float*)d_in[2];
    const float* Wrel0    = (const float*)d_in[3];
    const float* brel0    = (const float*)d_in[4];
    const float* Wroot0   = (const float*)d_in[5];
    const float* Wrel_mid = (const float*)d_in[6];
    const float* brel_mid = (const float*)d_in[7];
    const float* Wroot_mid= (const float*)d_in[8];
    const float* WrelL    = (const float*)d_in[9];
    const float* brelL    = (const float*)d_in[10];
    const float* WrootL   = (const float*)d_in[11];
    float* out = (float*)d_out;

    const int* src  = ei;
    const int* dstp = ei + NE;

    char* w = (char*)d_ws;
    size_t o = 0;
    auto alloc = [&](size_t b) -> void* {
        void* r = (void*)(w + o);
        o += (b + 255) & ~(size_t)255;
        return r;
    };
    int*      offs  = (int*)alloc((size_t)(NN + 1) * 4);
    int*      bcnt  = (int*)alloc((size_t)NBKT * 4);
    int*      bbase = (int*)alloc((size_t)(NBKT + 1) * 4);
    int*      bcur  = (int*)alloc((size_t)NBKT * 4);
    int2*     pairs = (int2*)alloc((size_t)NE * 8);
    float*    H     = (float*)alloc((size_t)NN * HID * 4);   // 25.6 MB
    uint16_t* Gb    = (uint16_t*)alloc((size_t)NN * HID * 2);// 12.8 MB
    float*    R     = (float*)alloc((size_t)NN * HID * 4);   // 25.6 MB
    // bpairs (NE*8B = 12.8MB) aliases H: dead before k_layer0 writes H
    int2*  bpairs = (int2*)H;
    // scalar aliases into Gb region (dead at those program points)
    float* agg0 = (float*)Gb;          // used before first k_pre2
    float* sarr = (float*)Gb;          // used after last k_aggrelu consumed Gb
    float* rarr = (float*)Gb + NN;

    hipMemsetAsync(bcnt, 0, (size_t)NBKT * 4, stream);

    // CSR build
    k_bhist<<<512, 256, 0, stream>>>(dstp, bcnt);
    k_bscan<<<1, 512, 0, stream>>>(bcnt, bbase, bcur, offs);
    k_bpart<<<NTILE, 256, 0, stream>>>(src, dstp, ew, bcur, bpairs);
    k_bcsr<<<NBKT, 256, 0, stream>>>(bbase, bpairs, offs, pairs);

    // layer 0 (1-channel input)
    k_agg_scalar<<<(NN + 255) / 256, 256, 0, stream>>>(offs, pairs, x, agg0);
    k_layer0<<<(NN * HID) / 256, 256, 0, stream>>>(agg0, x, Wrel0, brel0, Wroot0, H);

    // 3 middle layers
    for (int l = 0; l < 3; l++) {
        k_pre2<<<2 * PREB, 256, 0, stream>>>(
            H, Wrel_mid + (size_t)l * HID * HID,
            Wroot_mid + (size_t)l * HID * HID, brel_mid + (size_t)l * HID, Gb, R);
        k_aggrelu<<<(NN / 4 * 64) / 256, 256, 0, stream>>>(
            offs, pairs, (const uint32_t*)Gb, R, H);
    }

    // last layer: push WrelL through segment_sum -> scalar aggregation
    k_lastdot<<<(NN * HID + 255) / 256, 256, 0, stream>>>(H, WrelL, WrootL, sarr, rarr);
    k_last<<<(NN + 255) / 256, 256, 0, stream>>>(offs, pairs, sarr, rarr, brelL, out);
}